// Round 6
// baseline (1295.010 us; speedup 1.0000x reference)
//
#include <hip/hip_runtime.h>
#include <hip/hip_bf16.h>

// HunyuanTopKGate: x[4096,4096] fp32, wg[64,4096] fp32 ->
//   combine_weights [T,E,C] fp32 ++ dispatch_mask [T,E,C] (as fp32 0/1)
// C = out_size/(2*T*E) = 2268 measured -> 4.76 GB output zero-fill (~760us
// at the 6.3 TB/s ceiling) is the roofline pole.
//
// Round 6: abandon fp64 MFMA (two layout theories failed; repair tail ~500us
// both times -> gfx950 f64 MFMA layout remains unknown). Instead:
//  (a) vector-fp64 GEMM with 4x4 register blocking: instruction floor
//      ~1.67e7 wave-dfma / 1024 SIMD * ~4cyc ~ 27us + cvt/LDS -> ~40-60us
//      (vs round-1's 550us at 1x4 blocking, vs repair's ~400us untiled).
//      fp64 is numerically REQUIRED: fp32-class logit error (~3e-7) risks
//      top-k tie flips vs the numpy ref; fp64 (~1e-13) is safe.
//  (b) fuse the 4.76 GB zero-fill INTO the same dispatch as the GEMM
//      (gemm blocks first, then grid-stride fill blocks): fill is HBM-write
//      bound, gemm is VALU-bound -> they co-schedule (m114), hiding the
//      GEMM entirely under the fill. Same-stream serialization removed.
// verify+repair insurance kept one more round (guards a tiling bug).

#define TOK 4096
#define HID 4096
#define NE  64
#define NK  8
#define FILLB 2048

// ---------------- 1. fused: fp64-vector GEMM + output zero-fill ----------
// gemm blocks [0, 64*nsplit): tile 64 tokens x 64 experts, split-K.
//   thread (256/blk): te=tid&15 -> experts te*4..+3; tt=tid>>4 -> tokens
//   tt*4..+3; 16 fp64 accumulators; LDS f32 tiles, cvt on use.
//   wsf stride 65: w-read bank = (4*te + 65j + k) mod 32 -> only te,te+8
//   collide = 2-way = free (m136). xs reads broadcast (16 lanes same addr).
// fill blocks [64*nsplit, +FILLB): grid-stride float4 zero of d_out.
__global__ __launch_bounds__(256) void fused_gemm_fill(
    const float* __restrict__ x, const float* __restrict__ wg,
    double* __restrict__ partial, int kchunk, int nsplit,
    float* __restrict__ out, size_t n4, int* __restrict__ flag) {
  __shared__ float xs [64][68];   // 17.4 KB, rows 16B-aligned (272B stride)
  __shared__ float wsf[64][65];   // 16.6 KB
  const int tid = threadIdx.x;
  const int GB  = 64 * nsplit;

  if ((int)blockIdx.x >= GB) {
    // ---------------- fill ----------------
    const int fb = (int)blockIdx.x - GB;
    const float4 z4 = make_float4(0.f, 0.f, 0.f, 0.f);
    float4* o4 = (float4*)out;
    for (size_t i = (size_t)fb * 256 + tid; i < n4; i += (size_t)FILLB * 256)
      o4[i] = z4;
    return;
  }

  // ---------------- gemm ----------------
  if (blockIdx.x == 0 && tid == 0) *flag = 0;   // clear verify flag
  const int bt   = (int)blockIdx.x & 63;        // token tile
  const int slab = (int)blockIdx.x >> 6;        // k-split slab
  const int t0 = bt * 64;
  const int k0 = slab * kchunk;
  const int te = tid & 15;
  const int tt = tid >> 4;
  const int lrow = tid >> 2;          // staging: 4 threads per row
  const int lc   = (tid & 3) * 16;    // 16 floats per thread

  double acc[4][4];
#pragma unroll
  for (int i = 0; i < 4; ++i)
#pragma unroll
    for (int j = 0; j < 4; ++j) acc[i][j] = 0.0;

  for (int s = 0; s < kchunk; s += 64) {
    const int kk = k0 + s;
#pragma unroll
    for (int j = 0; j < 4; ++j) {
      float4 xv = *(const float4*)&x [(size_t)(t0 + lrow) * HID + kk + lc + 4 * j];
      *(float4*)&xs[lrow][lc + 4 * j] = xv;
      float4 wv = *(const float4*)&wg[(size_t)lrow * HID + kk + lc + 4 * j];
      wsf[lrow][lc + 4 * j + 0] = wv.x;
      wsf[lrow][lc + 4 * j + 1] = wv.y;
      wsf[lrow][lc + 4 * j + 2] = wv.z;
      wsf[lrow][lc + 4 * j + 3] = wv.w;
    }
    __syncthreads();
#pragma unroll 4
    for (int k4 = 0; k4 < 16; ++k4) {
      const int kb = k4 * 4;
      double dx[4][4];
#pragma unroll
      for (int i = 0; i < 4; ++i) {
        float4 xv = *(const float4*)&xs[tt * 4 + i][kb];
        dx[i][0] = (double)xv.x; dx[i][1] = (double)xv.y;
        dx[i][2] = (double)xv.z; dx[i][3] = (double)xv.w;
      }
#pragma unroll
      for (int j = 0; j < 4; ++j) {
        const double w0 = (double)wsf[te * 4 + j][kb + 0];
        const double w1 = (double)wsf[te * 4 + j][kb + 1];
        const double w2 = (double)wsf[te * 4 + j][kb + 2];
        const double w3 = (double)wsf[te * 4 + j][kb + 3];
#pragma unroll
        for (int i = 0; i < 4; ++i)
          acc[i][j] = fma(dx[i][0], w0,
                      fma(dx[i][1], w1,
                      fma(dx[i][2], w2,
                      fma(dx[i][3], w3, acc[i][j]))));
      }
    }
    __syncthreads();
  }

  double* base = partial + (size_t)slab * TOK * NE;
#pragma unroll
  for (int i = 0; i < 4; ++i)
#pragma unroll
    for (int j = 0; j < 4; ++j)
      base[(size_t)(t0 + tt * 4 + i) * NE + te * 4 + j] = acc[i][j];
}

// ---------------- 1b. verify: sample 512 logits vs exact fp64 dots --------
__global__ __launch_bounds__(256) void verify_kernel(
    const float* __restrict__ x, const float* __restrict__ wg,
    const double* __restrict__ partial, int nsplit, int* __restrict__ flag) {
  const int gid  = blockIdx.x * blockDim.x + threadIdx.x;
  const int wid  = gid >> 6;          // 0..511
  const int lane = gid & 63;
  const int t = (wid * 521) & (TOK - 1);
  const int e = wid & 63;
  double acc = 0.0;
  for (int k = lane; k < HID; k += 64)
    acc = fma((double)x[(size_t)t * HID + k], (double)wg[(size_t)e * HID + k], acc);
#pragma unroll
  for (int off = 32; off; off >>= 1) acc += __shfl_xor(acc, off);
  if (lane == 0) {
    double got = 0.0;
    for (int p = 0; p < nsplit; ++p)
      got += partial[(size_t)p * TOK * NE + (size_t)t * NE + e];
    if (!(fabs(got - acc) <= 1e-6)) atomicOr(flag, 1);  // NaN-safe
  }
}

// ---------------- 1c. repair: full vector-fp64 recompute if flag set ------
__global__ __launch_bounds__(256) void repair_gemm(
    const float* __restrict__ x, const float* __restrict__ wg,
    double* __restrict__ partial, int nsplit, const int* __restrict__ flag) {
  if (*(volatile const int*)flag == 0) return;
  const int gid = blockIdx.x * 256 + threadIdx.x;   // 0..262143
  const int t = gid >> 6;
  const int e = gid & 63;
  double acc = 0.0;
  for (int k = 0; k < HID; ++k)
    acc = fma((double)x[(size_t)t * HID + k], (double)wg[(size_t)e * HID + k], acc);
  partial[(size_t)t * NE + e] = acc;
  for (int p = 1; p < nsplit; ++p)
    partial[(size_t)p * TOK * NE + (size_t)t * NE + e] = 0.0;
}

// ---------------- 2. softmax + top-8 per token (one wave64/token) ----------
__global__ __launch_bounds__(256) void topk_kernel(
    const double* __restrict__ partial, int nsplit,
    int* __restrict__ idx_kt, float* __restrict__ w_kt) {
  const int gid  = blockIdx.x * blockDim.x + threadIdx.x;
  const int t    = gid >> 6;
  const int lane = gid & 63;

  double v = 0.0;
  for (int p = 0; p < nsplit; ++p)
    v += partial[(size_t)p * TOK * NE + (size_t)t * NE + lane];

  double m = v;
#pragma unroll
  for (int off = 32; off; off >>= 1) {
    double o = __shfl_xor(m, off);
    m = o > m ? o : m;
  }
  double g = exp(v - m);
  double s = g;
#pragma unroll
  for (int off = 32; off; off >>= 1) s += __shfl_xor(s, off);
  double gate = g / s;

  float key = (float)gate;    // fp32-rounded selection key, tie -> lower idx
  double ssel = 0.0;
  int my_k = -1;
#pragma unroll
  for (int k = 0; k < NK; ++k) {
    float bv = key;
    int   bi = lane;
#pragma unroll
    for (int off = 32; off; off >>= 1) {
      float ov = __shfl_xor(bv, off);
      int   oi = __shfl_xor(bi, off);
      if (ov > bv || (ov == bv && oi < bi)) { bv = ov; bi = oi; }
    }
    ssel += __shfl(gate, bi);
    if (lane == bi) { my_k = k; key = -1.0f; }
  }
  double gs = ssel;
  const double eps = (double)1.1920929e-07f;
  if (gs < eps) gs = eps;

  if (my_k >= 0) {
    idx_kt[my_k * TOK + t] = lane;
    w_kt [my_k * TOK + t] = (float)(gate / gs);
  }
}

// ---------------- 3. ranks: stable prefix count per expert --------------
__global__ __launch_bounds__(1024) void rank_kernel(
    const int* __restrict__ idx_kt, int* __restrict__ rank_kt) {
  const int e    = blockIdx.x;
  const int tid  = threadIdx.x;
  const int lane = tid & 63;
  const int w    = tid >> 6;          // 0..15
  __shared__ int wt[16];
  int running = 0;
  const unsigned long long below = (1ull << lane) - 1ull;

  for (int i0 = 0; i0 < NK * TOK; i0 += 1024) {
    const int i = i0 + tid;
    const bool mhit = (idx_kt[i] == e);
    unsigned long long mask = __ballot(mhit);
    if (lane == 0) wt[w] = __popcll(mask);
    __syncthreads();
    int woff = 0, tot = 0;
#pragma unroll
    for (int j = 0; j < 16; ++j) {
      int c = wt[j];
      tot += c;
      if (j < w) woff += c;
    }
    if (mhit) rank_kt[i] = running + woff + __popcll(mask & below);
    running += tot;
    __syncthreads();
  }
}

// ---------------- 4. scatter the 32768 nonzeros ----------------
__global__ __launch_bounds__(256) void scatter_kernel(
    const int* __restrict__ idx_kt, const int* __restrict__ rank_kt,
    const float* __restrict__ w_kt, float* __restrict__ out, int C) {
  const int i = blockIdx.x * 256 + threadIdx.x;   // 0..32767, = k*TOK + t
  const int t = i & (TOK - 1);
  const int e = idx_kt[i];
  const int c = rank_kt[i];
  const float wv = w_kt[i];
  if (e >= 0 && e < NE && c >= 0 && c < C) {
    size_t off = ((size_t)t * NE + e) * (size_t)C + (size_t)c;
    out[off] = wv;                                // combine_weights
    out[(size_t)TOK * NE * C + off] = 1.0f;       // dispatch_mask
  }
}

extern "C" void kernel_launch(void* const* d_in, const int* in_sizes, int n_in,
                              void* d_out, int out_size, void* d_ws, size_t ws_size,
                              hipStream_t stream) {
  const float* x  = (const float*)d_in[0];   // [4096,4096]
  const float* wg = (const float*)d_in[1];   // [64,4096]
  float* out = (float*)d_out;

  const int C = out_size / (2 * TOK * NE);   // capacity from output size

  const size_t slab = (size_t)TOK * NE * sizeof(double);   // 2 MB per partial
  const size_t tail = 3 * (size_t)NK * TOK * sizeof(int);  // idx+rank+w
  int nsplit = 8;
  while (nsplit > 1 && (size_t)nsplit * slab + tail + 64 > ws_size) nsplit >>= 1;
  const int kchunk = HID / nsplit;

  char* ws = (char*)d_ws;
  double* partial = (double*)ws;
  int*    idx_kt  = (int*)  (ws + (size_t)nsplit * slab);
  int*    rank_kt = (int*)  (ws + (size_t)nsplit * slab + (size_t)NK * TOK * 4);
  float*  w_kt    = (float*)(ws + (size_t)nsplit * slab + (size_t)NK * TOK * 8);
  int*    flag    = (int*)  (ws + (size_t)nsplit * slab + tail);

  const size_t n4 = (size_t)out_size >> 2;   // out_size divisible by 4

  // one dispatch: gemm blocks first (start immediately), fill blocks behind
  fused_gemm_fill<<<64 * nsplit + FILLB, 256, 0, stream>>>(
      x, wg, partial, kchunk, nsplit, out, n4, flag);
  verify_kernel  <<<128, 256, 0, stream>>>(x, wg, partial, nsplit, flag);
  repair_gemm    <<<TOK * NE / 256, 256, 0, stream>>>(x, wg, partial, nsplit, flag);
  topk_kernel    <<<TOK * 64 / 256, 256, 0, stream>>>(partial, nsplit, idx_kt, w_kt);
  rank_kernel    <<<NE, 1024, 0, stream>>>(idx_kt, rank_kt);
  scatter_kernel <<<NK * TOK / 256, 256, 0, stream>>>(idx_kt, rank_kt, w_kt, out, C);
}